// Round 14
// baseline (76.091 us; speedup 1.0000x reference)
//
#include <hip/hip_runtime.h>
#include <math.h>

#define NB 8
#define NHEADS 8
#define NDK 32
#define NDV 64
#define NSEQ 1024
#define NCIN 256

typedef __attribute__((ext_vector_type(8))) short bf16x8;
typedef __attribute__((ext_vector_type(4))) float f32x4;
typedef __attribute__((ext_vector_type(16))) float f32x16;

#define MFMA16(A, B, C) __builtin_amdgcn_mfma_f32_16x16x32_bf16(A, B, C, 0, 0, 0)
#define MFMA32(A, B, C) __builtin_amdgcn_mfma_f32_32x32x16_bf16(A, B, C, 0, 0, 0)

// log2e folded constants: logits2 = (q*SC2)·k + pe*PE2, SC2 pre-folded into Q weights
#define SC2 0.2550347873f
#define PE2 8.1611156f

__device__ __forceinline__ short f2bf(float f) {
    union { float f; unsigned u; } v; v.f = f;
    unsigned r = v.u + 0x7FFFu + ((v.u >> 16) & 1u);
    return (short)(r >> 16);
}

__device__ __forceinline__ unsigned cvt_pk_bf16(float lo, float hi) {
    unsigned r;
    asm("v_cvt_pk_bf16_f32 %0, %1, %2" : "=v"(r) : "v"(lo), "v"(hi));
    return r;
}

// async global->LDS, 16B/lane. LDS dest must be wave-uniform base (HW adds lane*16).
__device__ __forceinline__ void gload16(const short* g, short* l) {
    __builtin_amdgcn_global_load_lds(
        (const __attribute__((address_space(1))) void*)g,
        (__attribute__((address_space(3))) void*)l, 16, 0, 0);
}

// ---------------- K0: fused {x transpose} + {BN fold + bf16} + {bias table build} ----------------
// blocks [0,512): transpose x -> Xt bf16
// blocks [512,1536): BN fold into Wqkv (Q rows pre-scaled by SC2)
// blocks [1536,1792): Wo convert
// blocks [1792,2048): bias table Bias[h][drb][lane][16] f32 (register-layout-matched)
__global__ __launch_bounds__(256) void prep_trans_kernel(
    const float* __restrict__ x, short* __restrict__ Xt,
    const float* __restrict__ wq, const float* __restrict__ qg, const float* __restrict__ qb,
    const float* __restrict__ qm, const float* __restrict__ qv,
    const float* __restrict__ wk, const float* __restrict__ kg, const float* __restrict__ kb,
    const float* __restrict__ km, const float* __restrict__ kv,
    const float* __restrict__ wv, const float* __restrict__ vg, const float* __restrict__ vb,
    const float* __restrict__ vm, const float* __restrict__ vv,
    const float* __restrict__ wo, const float* __restrict__ pos_emb,
    short* __restrict__ Wqkv, float* __restrict__ Bqkv, short* __restrict__ Wo,
    float* __restrict__ Bias)
{
    __shared__ float tile[64][65];
    int bid = blockIdx.x, t = threadIdx.x;
    if (bid < 512) {
        int p0 = (bid & 15) * 64, c0 = ((bid >> 4) & 3) * 64, b = bid >> 6;
        int tp = t & 63, tr = t >> 6;
        const float* xb = x + ((size_t)b * NCIN + c0) * NSEQ + p0;
#pragma unroll
        for (int i = 0; i < 16; ++i) {
            int cl = tr * 16 + i;
            tile[cl][tp] = xb[(size_t)cl * NSEQ + tp];
        }
        __syncthreads();
        short* xt = Xt + ((size_t)b * NSEQ + p0) * NCIN + c0;
#pragma unroll
        for (int i = 0; i < 16; ++i) {
            int pl = tr * 16 + i;
            xt[(size_t)pl * NCIN + tp] = f2bf(tile[tp][pl]);
        }
    } else if (bid < 1792) {
        int row = bid - 512;
        if (row < 1024) {
            const float *w, *g, *be, *mu, *va; int o; float sc;
            if (row < 256)      { w = wq; o = row;       g = qg; be = qb; mu = qm; va = qv; sc = SC2; }
            else if (row < 512) { w = wk; o = row - 256; g = kg; be = kb; mu = km; va = kv; sc = 1.f; }
            else                { w = wv; o = row - 512; g = vg; be = vb; mu = vm; va = vv; sc = 1.f; }
            float inv = g[o] * rsqrtf(va[o] + 1e-5f) * sc;
            Wqkv[row * NCIN + t] = f2bf(w[o * NCIN + t] * inv);
            if (t == 0) Bqkv[row] = (be[o] - mu[o] * (g[o] * rsqrtf(va[o] + 1e-5f))) * sc;
        } else {
            int o = row - 1024;
            Wo[o * 512 + t]       = f2bf(wo[o * 512 + t]);
            Wo[o * 512 + 256 + t] = f2bf(wo[o * 512 + 256 + t]);
        }
    } else {
        // bias table: value(l, 4a+u) = pos_emb[(drb*32 + |ql - 4hi - 8a - u|)*8 + h] * PE2
        int e = bid - 1792;
        int h = e >> 5, drb = e & 31;
        int l = t >> 2, a = t & 3;
        int ql = l & 31, hi4 = (l >> 5) * 4;
        float4 w;
#pragma unroll
        for (int u = 0; u < 4; ++u) {
            int dc = ql - hi4 - 8 * a - u; dc = dc < 0 ? -dc : dc;
            ((float*)&w)[u] = pos_emb[(drb * 32 + dc) * NHEADS + h] * PE2;
        }
        *(float4*)(Bias + (((size_t)(h * 32 + drb) * 64) + l) * 16 + a * 4) = w;
    }
}

// ---------------- K2: QKV projection GEMM (global_load_lds staging) ----------------
__global__ __launch_bounds__(256) void qkv_gemm(
    const short* __restrict__ Xt, const short* __restrict__ Wqkv, const float* __restrict__ Bqkv,
    short* __restrict__ Qo, short* __restrict__ Ko, short* __restrict__ Vto)
{
    __shared__ short At[128][32];
    __shared__ short Bt[128][32];
    int b = blockIdx.z, p0 = blockIdx.x * 128, o0 = blockIdx.y * 128;
    int t = threadIdx.x, wave = t >> 6, lane = t & 63;
    int wr = wave >> 1, wc = wave & 1, lr = lane & 15, lg = lane >> 4;

    const short* Abase = Xt + ((size_t)b * NSEQ + p0) * NCIN;
    const short* Bbase = Wqkv + (size_t)o0 * NCIN;

    int srow = lane >> 2, scol = (lane & 3) * 8;
    int r0 = (wave * 2) * 16 + srow, r1 = (wave * 2 + 1) * 16 + srow;
    short* lA0 = &At[0][0] + (wave * 2) * 512;
    short* lA1 = &At[0][0] + (wave * 2 + 1) * 512;
    short* lB0 = &Bt[0][0] + (wave * 2) * 512;
    short* lB1 = &Bt[0][0] + (wave * 2 + 1) * 512;

    f32x4 acc[4][4];
#pragma unroll
    for (int m = 0; m < 4; ++m)
#pragma unroll
        for (int n = 0; n < 4; ++n) acc[m][n] = (f32x4){0.f, 0.f, 0.f, 0.f};

    for (int k0 = 0; k0 < NCIN; k0 += 32) {
        gload16(Abase + (size_t)r0 * NCIN + k0 + scol, lA0);
        gload16(Abase + (size_t)r1 * NCIN + k0 + scol, lA1);
        gload16(Bbase + (size_t)r0 * NCIN + k0 + scol, lB0);
        gload16(Bbase + (size_t)r1 * NCIN + k0 + scol, lB1);
        __syncthreads();
        bf16x8 af[4], bfr[4];
#pragma unroll
        for (int m = 0; m < 4; ++m) af[m] = *(const bf16x8*)&At[wr * 64 + m * 16 + lr][lg * 8];
#pragma unroll
        for (int n = 0; n < 4; ++n) bfr[n] = *(const bf16x8*)&Bt[wc * 64 + n * 16 + lr][lg * 8];
#pragma unroll
        for (int m = 0; m < 4; ++m)
#pragma unroll
            for (int n = 0; n < 4; ++n)
                acc[m][n] = MFMA16(af[m], bfr[n], acc[m][n]);
        __syncthreads();
    }

#pragma unroll
    for (int n = 0; n < 4; ++n) {
        int o = o0 + wc * 64 + n * 16 + lr;
        float bias = Bqkv[o];
#pragma unroll
        for (int m = 0; m < 4; ++m) {
            int pr = p0 + wr * 64 + m * 16 + lg * 4;
#pragma unroll
            for (int r = 0; r < 4; ++r) {
                float y = acc[m][n][r] + bias;
                short vv = f2bf(y);
                int p = pr + r;
                if (o < 256) {
                    int hh = o >> 5, d = o & 31;
                    Qo[(((size_t)b * NHEADS + hh) * NSEQ + p) * NDK + d] = vv;
                } else if (o < 512) {
                    int oo = o - 256, hh = oo >> 5, d = oo & 31;
                    Ko[(((size_t)b * NHEADS + hh) * NSEQ + p) * NDK + d] = vv;
                } else {
                    int oo = o - 512, hh = oo >> 6, d = oo & 63;
                    Vto[(((size_t)b * NHEADS + hh) * NDV + d) * NSEQ + p] = vv;
                }
            }
        }
    }
}

// ---------------- K3: flash attention + GELU (bias from GLOBAL table, off the LDS pipe) ----------------
// WG = 4 waves x 32q; sweep 1024 keys in 64-key tiles (R12 loop structure).
// The 16 bias values per (lane, subtile) come from a register-layout-matched global
// table via 4x dwordx4 on the idle VMEM pipe — deletes the 16 scalar ds_read_b32
// bias gathers that dominated the saturated LDS pipe (~50% of its issue).
__global__ __launch_bounds__(256) void attn_kernel(
    const short* __restrict__ Q, const short* __restrict__ K, const short* __restrict__ Vt,
    const float* __restrict__ Bias, short* __restrict__ Xg)
{
    __shared__ short Klds[2][64][36];    // [buf][key][d]
    __shared__ short Vlds[2][64][68];    // [buf][d][j]
    __shared__ short tb[4][32][68];      // per-wave epilogue transpose

    int bid = blockIdx.x;
    int h = bid & 7;                     // head per XCD: K/V + Bias slice L2-hot
    int qt = (bid >> 3) & 7;
    int b = bid >> 6;
    int t = threadIdx.x, wave = t >> 6, l = t & 63, ql = l & 31, hi = l >> 5;

    size_t bh = (size_t)b * NHEADS + h;
    const short* Qb = Q + bh * NSEQ * NDK;
    const short* Kb = K + bh * NSEQ * NDK;
    const short* Vb = Vt + bh * NDV * NSEQ;
    const float* Bl = Bias + ((size_t)h * 32 * 64 + l) * 16;   // + drb*64*16 + a*4

    int q0 = qt * 128 + wave * 32;
    int iq = q0 + ql;
    int qr = iq >> 5;

    bf16x8 qf0 = *(const bf16x8*)(Qb + (size_t)iq * NDK + hi * 8);
    bf16x8 qf1 = *(const bf16x8*)(Qb + (size_t)iq * NDK + 16 + hi * 8);

    int krow = t >> 2, kcol = (t & 3) * 8;
    int vrow = t >> 3, vcol = (t & 7) * 8;

    // prologue: stage tile 0 into buf 0
    {
        int4 kreg  = *(const int4*)(Kb + (size_t)krow * NDK + kcol);
        int4 vreg0 = *(const int4*)(Vb + (size_t)vrow * NSEQ + vcol);
        int4 vreg1 = *(const int4*)(Vb + (size_t)(vrow + 32) * NSEQ + vcol);
        *(int4*)&Klds[0][krow][kcol] = kreg;
        *(int4*)&Vlds[0][vrow][vcol] = vreg0;
        *(int4*)&Vlds[0][vrow + 32][vcol] = vreg1;
    }
    __syncthreads();   // tile 0 ready

    float lsum = 0.f;
    f32x16 O0, O1;
#pragma unroll
    for (int r = 0; r < 16; ++r) { O0[r] = 0.f; O1[r] = 0.f; }

    int cur = 0;
    for (int jt = 0; jt < 16; ++jt) {
        int4 kreg, vreg0, vreg1;
        if (jt < 15) {   // issue next-tile K/V loads early
            int j0n = (jt + 1) * 64;
            kreg  = *(const int4*)(Kb + (size_t)(j0n + krow) * NDK + kcol);
            vreg0 = *(const int4*)(Vb + (size_t)vrow * NSEQ + j0n + vcol);
            vreg1 = *(const int4*)(Vb + (size_t)(vrow + 32) * NSEQ + j0n + vcol);
        }

        // bias fragments for both subtiles of THIS tile (VMEM; latency hides under compute)
        int dr0 = qr - 2 * jt;     dr0 = dr0 < 0 ? -dr0 : dr0;
        int dr1 = qr - 2 * jt - 1; dr1 = dr1 < 0 ? -dr1 : dr1;
        const float4* bp0 = (const float4*)(Bl + (size_t)dr0 * 1024);
        const float4* bp1 = (const float4*)(Bl + (size_t)dr1 * 1024);
        float4 b0_0 = bp0[0], b0_1 = bp0[1], b0_2 = bp0[2], b0_3 = bp0[3];
        float4 b1_0 = bp1[0], b1_1 = bp1[1], b1_2 = bp1[2], b1_3 = bp1[3];

#pragma unroll
        for (int s = 0; s < 2; ++s) {
            bf16x8 kf0 = *(const bf16x8*)&Klds[cur][s * 32 + ql][hi * 8];
            bf16x8 kf1 = *(const bf16x8*)&Klds[cur][s * 32 + ql][16 + hi * 8];

            // C-init = bias fragments (S[4a+u] = Bias[h][drb][l][4a+u])
            f32x16 S;
            if (s == 0) {
#pragma unroll
                for (int u = 0; u < 4; ++u) {
                    S[0 + u]  = ((float*)&b0_0)[u];
                    S[4 + u]  = ((float*)&b0_1)[u];
                    S[8 + u]  = ((float*)&b0_2)[u];
                    S[12 + u] = ((float*)&b0_3)[u];
                }
            } else {
#pragma unroll
                for (int u = 0; u < 4; ++u) {
                    S[0 + u]  = ((float*)&b1_0)[u];
                    S[4 + u]  = ((float*)&b1_1)[u];
                    S[8 + u]  = ((float*)&b1_2)[u];
                    S[12 + u] = ((float*)&b1_3)[u];
                }
            }
            S = MFMA32(kf0, qf0, S);
            S = MFMA32(kf1, qf1, S);

            bf16x8 vf[4];
#pragma unroll
            for (int dn = 0; dn < 2; ++dn)
#pragma unroll
                for (int ks = 0; ks < 2; ++ks)
                    vf[dn * 2 + ks] = *(const bf16x8*)&Vlds[cur][dn * 32 + ql][s * 32 + ks * 16 + hi * 8];

            // P = exp2(logits2) directly (|logits2| << 127, shift-invariant)
#pragma unroll
            for (int r = 0; r < 16; ++r) S[r] = __builtin_amdgcn_exp2f(S[r]);

            {   // lsum: 15-add tree
                float a0 = S[0] + S[1],   a1 = S[2] + S[3];
                float a2 = S[4] + S[5],   a3 = S[6] + S[7];
                float a4 = S[8] + S[9],   a5 = S[10] + S[11];
                float a6 = S[12] + S[13], a7 = S[14] + S[15];
                float b0 = a0 + a1, b1 = a2 + a3, b2 = a4 + a5, b3 = a6 + a7;
                lsum += (b0 + b1) + (b2 + b3);
            }

            unsigned pk[4][2];
#pragma unroll
            for (int a = 0; a < 4; ++a)
#pragma unroll
                for (int u = 0; u < 2; ++u)
                    pk[a][u] = cvt_pk_bf16(S[4 * a + 2 * u], S[4 * a + 2 * u + 1]);

#pragma unroll
            for (int ks = 0; ks < 2; ++ks) {
                unsigned u0 = pk[2 * ks][0], u2 = pk[2 * ks + 1][0];
                unsigned u1 = pk[2 * ks][1], u3 = pk[2 * ks + 1][1];
                asm("v_permlane32_swap_b32 %0, %1" : "+v"(u0), "+v"(u2));
                asm("v_permlane32_swap_b32 %0, %1" : "+v"(u1), "+v"(u3));
                union { bf16x8 v; unsigned u[4]; } pf;
                pf.u[0] = u0; pf.u[1] = u1; pf.u[2] = u2; pf.u[3] = u3;
                O0 = MFMA32(vf[ks], pf.v, O0);
                O1 = MFMA32(vf[2 + ks], pf.v, O1);
            }
        }

        if (jt < 15) {
            // buf[cur^1]'s last readers finished before the PREVIOUS barrier:
            // one barrier per iteration suffices.
            *(int4*)&Klds[cur ^ 1][krow][kcol] = kreg;
            *(int4*)&Vlds[cur ^ 1][vrow][vcol] = vreg0;
            *(int4*)&Vlds[cur ^ 1][vrow + 32][vcol] = vreg1;
            __syncthreads();
            cur ^= 1;
        }
    }

    lsum += __shfl_xor(lsum, 32);
    float inv = 1.0f / lsum;

    // per-wave epilogue: GELU in regs, transpose via private tb slab, 16B stores
    short (*tw)[68] = tb[wave];
#pragma unroll
    for (int dn = 0; dn < 2; ++dn)
#pragma unroll
        for (int a = 0; a < 4; ++a) {
            short4 w;
#pragma unroll
            for (int bb = 0; bb < 4; ++bb) {
                float v = (dn ? O1[4 * a + bb] : O0[4 * a + bb]) * inv;
                v = 0.5f * v * (1.f + erff(v * 0.70710678118654752f));  // exact GELU
                ((short*)&w)[bb] = f2bf(v);
            }
            *(short4*)&tw[ql][dn * 32 + 8 * a + 4 * hi] = w;
        }
#pragma unroll
    for (int c = 0; c < 4; ++c) {
        int4 val = *(const int4*)&tw[ql][(hi * 4 + c) * 8];
        *(int4*)(Xg + ((size_t)b * NSEQ + q0 + ql) * 512 + h * 64 + (hi * 4 + c) * 8) = val;
    }
}

// ---------------- K4: output projection + bias + BN (128x64, global_load_lds staging) ----------------
__global__ __launch_bounds__(256) void out_gemm(
    const short* __restrict__ Xg, const short* __restrict__ Wo,
    const float* __restrict__ bo, const float* __restrict__ og, const float* __restrict__ ob,
    const float* __restrict__ om, const float* __restrict__ ov,
    float* __restrict__ out)
{
    __shared__ short At[128][32];
    __shared__ short Bt[64][32];
    int mt = blockIdx.x, nt = blockIdx.y;
    int t = threadIdx.x, wave = t >> 6, lane = t & 63;
    int wr = wave >> 1, wc = wave & 1, lr = lane & 15, lg = lane >> 4;
    int row0 = mt * 128, o0 = nt * 64;

    int srow = lane >> 2, scol = (lane & 3) * 8;
    int rA0 = (wave * 2) * 16 + srow, rA1 = (wave * 2 + 1) * 16 + srow;
    int rB  = wave * 16 + srow;
    short* lA0 = &At[0][0] + (wave * 2) * 512;
    short* lA1 = &At[0][0] + (wave * 2 + 1) * 512;
    short* lB  = &Bt[0][0] + wave * 512;

    f32x4 acc[4][2];
#pragma unroll
    for (int m = 0; m < 4; ++m)
#pragma unroll
        for (int n = 0; n < 2; ++n) acc[m][n] = (f32x4){0.f, 0.f, 0.f, 0.f};

    for (int k0 = 0; k0 < 512; k0 += 32) {
        gload16(Xg + (size_t)(row0 + rA0) * 512 + k0 + scol, lA0);
        gload16(Xg + (size_t)(row0 + rA1) * 512 + k0 + scol, lA1);
        gload16(Wo + (size_t)(o0 + rB) * 512 + k0 + scol, lB);
        __syncthreads();
        bf16x8 af[4], bfr[2];
#pragma unroll
        for (int m = 0; m < 4; ++m) af[m] = *(const bf16x8*)&At[wr * 64 + m * 16 + lr][lg * 8];
#pragma unroll
        for (int n = 0; n < 2; ++n) bfr[n] = *(const bf16x8*)&Bt[wc * 32 + n * 16 + lr][lg * 8];
#pragma unroll
        for (int m = 0; m < 4; ++m)
#pragma unroll
            for (int n = 0; n < 2; ++n)
                acc[m][n] = MFMA16(af[m], bfr[n], acc[m][n]);
        __syncthreads();
    }

    int b = row0 >> 10;
    int pbase = row0 & 1023;
#pragma unroll
    for (int n = 0; n < 2; ++n) {
        int o = o0 + wc * 32 + n * 16 + lr;
        float inv = og[o] * rsqrtf(ov[o] + 1e-5f);
        float off = bo[o] * inv + ob[o] - om[o] * inv;
        float* dst = out + ((size_t)b * 256 + o) * 1024 + pbase;
#pragma unroll
        for (int m = 0; m < 4; ++m)
#pragma unroll
            for (int r = 0; r < 4; ++r) {
                int p = wr * 64 + m * 16 + lg * 4 + r;
                dst[p] = acc[m][n][r] * inv + off;
            }
    }
}

// ---------------- launch ----------------
extern "C" void kernel_launch(void* const* d_in, const int* in_sizes, int n_in,
                              void* d_out, int out_size, void* d_ws, size_t ws_size,
                              hipStream_t stream) {
    const float* x     = (const float*)d_in[0];
    const float* wq    = (const float*)d_in[1];
    const float* qgam  = (const float*)d_in[2];
    const float* qbet  = (const float*)d_in[3];
    const float* qmu   = (const float*)d_in[4];
    const float* qvar  = (const float*)d_in[5];
    const float* wk    = (const float*)d_in[6];
    const float* kgam  = (const float*)d_in[7];
    const float* kbet  = (const float*)d_in[8];
    const float* kmu   = (const float*)d_in[9];
    const float* kvar  = (const float*)d_in[10];
    const float* wv    = (const float*)d_in[11];
    const float* vgam  = (const float*)d_in[12];
    const float* vbet  = (const float*)d_in[13];
    const float* vmu   = (const float*)d_in[14];
    const float* vvar  = (const float*)d_in[15];
    const float* wo    = (const float*)d_in[16];
    const float* bo    = (const float*)d_in[17];
    const float* ogam  = (const float*)d_in[18];
    const float* obet  = (const float*)d_in[19];
    const float* omu   = (const float*)d_in[20];
    const float* ovar  = (const float*)d_in[21];
    const float* pos_emb = (const float*)d_in[22];
    // d_in[23] pos_indices: recomputed analytically in-kernel

    char* ws = (char*)d_ws;
    short* Wqkv = (short*)(ws + 0);          // 524288
    float* Bqkv = (float*)(ws + 524288);     // 4096
    short* Wo   = (short*)(ws + 528384);     // 262144
    short* Xt   = (short*)(ws + 790528);     // 4 MB
    short* Qd   = (short*)(ws + 4984832);    // 4 MB
    short* Kd   = (short*)(ws + 9179136);    // 4 MB
    short* Vtd  = (short*)(ws + 13373440);   // 8 MB
    short* Xg   = (short*)(ws + 21762048);   // 8 MB (end 30150656)
    float* Bias = (float*)(ws + 30150656);   // 8*32*64*16*4 = 1 MB (end 31199232; ws >= 47 MB proven R11)

    prep_trans_kernel<<<2048, 256, 0, stream>>>(x, Xt,
                                                wq, qgam, qbet, qmu, qvar,
                                                wk, kgam, kbet, kmu, kvar,
                                                wv, vgam, vbet, vmu, vvar,
                                                wo, pos_emb, Wqkv, Bqkv, Wo, Bias);
    qkv_gemm<<<dim3(8, 8, NB), 256, 0, stream>>>(Xt, Wqkv, Bqkv, Qd, Kd, Vtd);
    attn_kernel<<<512, 256, 0, stream>>>(Qd, Kd, Vtd, Bias, Xg);
    out_gemm<<<dim3(64, 4), 256, 0, stream>>>(Xg, Wo, bo, ogam, obet, omu, ovar, (float*)d_out);
}

// Round 15
// 73.113 us; speedup vs baseline: 1.0407x; 1.0407x over previous
//
#include <hip/hip_runtime.h>
#include <math.h>

#define NB 8
#define NHEADS 8
#define NDK 32
#define NDV 64
#define NSEQ 1024
#define NCIN 256

typedef __attribute__((ext_vector_type(8))) short bf16x8;
typedef __attribute__((ext_vector_type(4))) float f32x4;
typedef __attribute__((ext_vector_type(16))) float f32x16;

#define MFMA16(A, B, C) __builtin_amdgcn_mfma_f32_16x16x32_bf16(A, B, C, 0, 0, 0)
#define MFMA32(A, B, C) __builtin_amdgcn_mfma_f32_32x32x16_bf16(A, B, C, 0, 0, 0)

// log2e folded constants: logits2 = (q*SC2)·k + pe*PE2, SC2 pre-folded into Q weights
#define SC2 0.2550347873f
#define PE2 8.1611156f

__device__ __forceinline__ short f2bf(float f) {
    union { float f; unsigned u; } v; v.f = f;
    unsigned r = v.u + 0x7FFFu + ((v.u >> 16) & 1u);
    return (short)(r >> 16);
}

__device__ __forceinline__ unsigned cvt_pk_bf16(float lo, float hi) {
    unsigned r;
    asm("v_cvt_pk_bf16_f32 %0, %1, %2" : "=v"(r) : "v"(lo), "v"(hi));
    return r;
}

// async global->LDS, 16B/lane. LDS dest must be wave-uniform base (HW adds lane*16).
__device__ __forceinline__ void gload16(const short* g, short* l) {
    __builtin_amdgcn_global_load_lds(
        (const __attribute__((address_space(1))) void*)g,
        (__attribute__((address_space(3))) void*)l, 16, 0, 0);
}

// ---------------- K0: fused {x transpose} + {BN fold + bf16 convert} ----------------
__global__ __launch_bounds__(256) void prep_trans_kernel(
    const float* __restrict__ x, short* __restrict__ Xt,
    const float* __restrict__ wq, const float* __restrict__ qg, const float* __restrict__ qb,
    const float* __restrict__ qm, const float* __restrict__ qv,
    const float* __restrict__ wk, const float* __restrict__ kg, const float* __restrict__ kb,
    const float* __restrict__ km, const float* __restrict__ kv,
    const float* __restrict__ wv, const float* __restrict__ vg, const float* __restrict__ vb,
    const float* __restrict__ vm, const float* __restrict__ vv,
    const float* __restrict__ wo,
    short* __restrict__ Wqkv, float* __restrict__ Bqkv, short* __restrict__ Wo)
{
    __shared__ float tile[64][65];
    int bid = blockIdx.x, t = threadIdx.x;
    if (bid < 512) {
        int p0 = (bid & 15) * 64, c0 = ((bid >> 4) & 3) * 64, b = bid >> 6;
        int tp = t & 63, tr = t >> 6;
        const float* xb = x + ((size_t)b * NCIN + c0) * NSEQ + p0;
#pragma unroll
        for (int i = 0; i < 16; ++i) {
            int cl = tr * 16 + i;
            tile[cl][tp] = xb[(size_t)cl * NSEQ + tp];
        }
        __syncthreads();
        short* xt = Xt + ((size_t)b * NSEQ + p0) * NCIN + c0;
#pragma unroll
        for (int i = 0; i < 16; ++i) {
            int pl = tr * 16 + i;
            xt[(size_t)pl * NCIN + tp] = f2bf(tile[tp][pl]);
        }
    } else {
        int row = bid - 512;
        if (row < 1024) {
            const float *w, *g, *be, *mu, *va; int o; float sc;
            if (row < 256)      { w = wq; o = row;       g = qg; be = qb; mu = qm; va = qv; sc = SC2; }
            else if (row < 512) { w = wk; o = row - 256; g = kg; be = kb; mu = km; va = kv; sc = 1.f; }
            else                { w = wv; o = row - 512; g = vg; be = vb; mu = vm; va = vv; sc = 1.f; }
            float inv = g[o] * rsqrtf(va[o] + 1e-5f) * sc;
            Wqkv[row * NCIN + t] = f2bf(w[o * NCIN + t] * inv);
            if (t == 0) Bqkv[row] = (be[o] - mu[o] * (g[o] * rsqrtf(va[o] + 1e-5f))) * sc;
        } else {
            int o = row - 1024;
            Wo[o * 512 + t]       = f2bf(wo[o * 512 + t]);
            Wo[o * 512 + 256 + t] = f2bf(wo[o * 512 + 256 + t]);
        }
    }
}

// ---------------- K2: QKV projection GEMM (global_load_lds staging) ----------------
__global__ __launch_bounds__(256) void qkv_gemm(
    const short* __restrict__ Xt, const short* __restrict__ Wqkv, const float* __restrict__ Bqkv,
    short* __restrict__ Qo, short* __restrict__ Ko, short* __restrict__ Vto)
{
    __shared__ short At[128][32];
    __shared__ short Bt[128][32];
    int b = blockIdx.z, p0 = blockIdx.x * 128, o0 = blockIdx.y * 128;
    int t = threadIdx.x, wave = t >> 6, lane = t & 63;
    int wr = wave >> 1, wc = wave & 1, lr = lane & 15, lg = lane >> 4;

    const short* Abase = Xt + ((size_t)b * NSEQ + p0) * NCIN;
    const short* Bbase = Wqkv + (size_t)o0 * NCIN;

    int srow = lane >> 2, scol = (lane & 3) * 8;
    int r0 = (wave * 2) * 16 + srow, r1 = (wave * 2 + 1) * 16 + srow;
    short* lA0 = &At[0][0] + (wave * 2) * 512;
    short* lA1 = &At[0][0] + (wave * 2 + 1) * 512;
    short* lB0 = &Bt[0][0] + (wave * 2) * 512;
    short* lB1 = &Bt[0][0] + (wave * 2 + 1) * 512;

    f32x4 acc[4][4];
#pragma unroll
    for (int m = 0; m < 4; ++m)
#pragma unroll
        for (int n = 0; n < 4; ++n) acc[m][n] = (f32x4){0.f, 0.f, 0.f, 0.f};

    for (int k0 = 0; k0 < NCIN; k0 += 32) {
        gload16(Abase + (size_t)r0 * NCIN + k0 + scol, lA0);
        gload16(Abase + (size_t)r1 * NCIN + k0 + scol, lA1);
        gload16(Bbase + (size_t)r0 * NCIN + k0 + scol, lB0);
        gload16(Bbase + (size_t)r1 * NCIN + k0 + scol, lB1);
        __syncthreads();
        bf16x8 af[4], bfr[4];
#pragma unroll
        for (int m = 0; m < 4; ++m) af[m] = *(const bf16x8*)&At[wr * 64 + m * 16 + lr][lg * 8];
#pragma unroll
        for (int n = 0; n < 4; ++n) bfr[n] = *(const bf16x8*)&Bt[wc * 64 + n * 16 + lr][lg * 8];
#pragma unroll
        for (int m = 0; m < 4; ++m)
#pragma unroll
            for (int n = 0; n < 4; ++n)
                acc[m][n] = MFMA16(af[m], bfr[n], acc[m][n]);
        __syncthreads();
    }

#pragma unroll
    for (int n = 0; n < 4; ++n) {
        int o = o0 + wc * 64 + n * 16 + lr;
        float bias = Bqkv[o];
#pragma unroll
        for (int m = 0; m < 4; ++m) {
            int pr = p0 + wr * 64 + m * 16 + lg * 4;
#pragma unroll
            for (int r = 0; r < 4; ++r) {
                float y = acc[m][n][r] + bias;
                short vv = f2bf(y);
                int p = pr + r;
                if (o < 256) {
                    int hh = o >> 5, d = o & 31;
                    Qo[(((size_t)b * NHEADS + hh) * NSEQ + p) * NDK + d] = vv;
                } else if (o < 512) {
                    int oo = o - 256, hh = oo >> 5, d = oo & 31;
                    Ko[(((size_t)b * NHEADS + hh) * NSEQ + p) * NDK + d] = vv;
                } else {
                    int oo = o - 512, hh = oo >> 6, d = oo & 63;
                    Vto[(((size_t)b * NHEADS + hh) * NDV + d) * NSEQ + p] = vv;
                }
            }
        }
    }
}

// ---------------- K3: flash attention + GELU (R12 best-known: bias-in-accumulator) ----------------
// WG = 4 waves x 32q = 128 q-rows of one (b,h); sweep 1024 keys in 64-key tiles.
// Q pre-scaled by SC2 -> S = MFMA(kf1,qf1, MFMA(kf0,qf0, C_bias)) -> exp2 directly.
__global__ __launch_bounds__(256) void attn_kernel(
    const short* __restrict__ Q, const short* __restrict__ K, const short* __restrict__ Vt,
    const float* __restrict__ pos_emb, short* __restrict__ Xg)
{
    __shared__ float peR[32][64];
    __shared__ short Klds[2][64][36];    // [buf][key][d]
    __shared__ short Vlds[2][64][68];    // [buf][d][j]
    __shared__ short tb[4][32][68];      // per-wave epilogue transpose

    int bid = blockIdx.x;
    int h = bid & 7;                     // head per XCD: K/V set 1.5MB/XCD (L2-fit)
    int qt = (bid >> 3) & 7;
    int b = bid >> 6;
    int t = threadIdx.x, wave = t >> 6, l = t & 63, ql = l & 31, hi = l >> 5;

    {   // build reversed bias table: peR[dr][y] = pe[dr*32 + |31-y|] * PE2
        int dr = t >> 3, y0 = (t & 7) * 8;
#pragma unroll
        for (int k = 0; k < 8; ++k) {
            int y = y0 + k;
            if (y < 63) {
                int d = 31 - y; d = d < 0 ? -d : d;
                peR[dr][y] = pos_emb[(dr * 32 + d) * NHEADS + h] * PE2;
            }
        }
    }

    size_t bh = (size_t)b * NHEADS + h;
    const short* Qb = Q + bh * NSEQ * NDK;
    const short* Kb = K + bh * NSEQ * NDK;
    const short* Vb = Vt + bh * NDV * NSEQ;

    int q0 = qt * 128 + wave * 32;
    int iq = q0 + ql;
    int qr = iq >> 5;
    int pebase = 31 - ql + 4 * hi;

    bf16x8 qf0 = *(const bf16x8*)(Qb + (size_t)iq * NDK + hi * 8);
    bf16x8 qf1 = *(const bf16x8*)(Qb + (size_t)iq * NDK + 16 + hi * 8);

    int krow = t >> 2, kcol = (t & 3) * 8;
    int vrow = t >> 3, vcol = (t & 7) * 8;

    // prologue: stage tile 0 into buf 0
    {
        int4 kreg  = *(const int4*)(Kb + (size_t)krow * NDK + kcol);
        int4 vreg0 = *(const int4*)(Vb + (size_t)vrow * NSEQ + vcol);
        int4 vreg1 = *(const int4*)(Vb + (size_t)(vrow + 32) * NSEQ + vcol);
        *(int4*)&Klds[0][krow][kcol] = kreg;
        *(int4*)&Vlds[0][vrow][vcol] = vreg0;
        *(int4*)&Vlds[0][vrow + 32][vcol] = vreg1;
    }
    __syncthreads();   // peR + tile 0 ready

    float lsum = 0.f;
    f32x16 O0, O1;
#pragma unroll
    for (int r = 0; r < 16; ++r) { O0[r] = 0.f; O1[r] = 0.f; }

    int cur = 0;
    for (int jt = 0; jt < 16; ++jt) {
        int4 kreg, vreg0, vreg1;
        if (jt < 15) {   // issue next-tile loads early; latency hides under compute
            int j0n = (jt + 1) * 64;
            kreg  = *(const int4*)(Kb + (size_t)(j0n + krow) * NDK + kcol);
            vreg0 = *(const int4*)(Vb + (size_t)vrow * NSEQ + j0n + vcol);
            vreg1 = *(const int4*)(Vb + (size_t)(vrow + 32) * NSEQ + j0n + vcol);
        }

#pragma unroll
        for (int s = 0; s < 2; ++s) {
            int jr = (jt * 64 + s * 32) >> 5;
            int drb = qr - jr; drb = drb < 0 ? -drb : drb;   // wave-uniform
            const float* per = &peR[drb][pebase];

            bf16x8 kf0 = *(const bf16x8*)&Klds[cur][s * 32 + ql][hi * 8];
            bf16x8 kf1 = *(const bf16x8*)&Klds[cur][s * 32 + ql][16 + hi * 8];

            // C-init = bias (S[r] needs per[jcr], jcr = (r&3)+8*(r>>2))
            f32x16 S;
#pragma unroll
            for (int a = 0; a < 4; ++a)
#pragma unroll
                for (int u = 0; u < 4; ++u)
                    S[4 * a + u] = per[8 * a + u];
            S = MFMA32(kf0, qf0, S);
            S = MFMA32(kf1, qf1, S);

            bf16x8 vf[4];
#pragma unroll
            for (int dn = 0; dn < 2; ++dn)
#pragma unroll
                for (int ks = 0; ks < 2; ++ks)
                    vf[dn * 2 + ks] = *(const bf16x8*)&Vlds[cur][dn * 32 + ql][s * 32 + ks * 16 + hi * 8];

            // P = exp2(logits2) directly (|logits2| << 127, shift-invariant)
#pragma unroll
            for (int r = 0; r < 16; ++r) S[r] = __builtin_amdgcn_exp2f(S[r]);

            {   // lsum: 15-add tree
                float a0 = S[0] + S[1],   a1 = S[2] + S[3];
                float a2 = S[4] + S[5],   a3 = S[6] + S[7];
                float a4 = S[8] + S[9],   a5 = S[10] + S[11];
                float a6 = S[12] + S[13], a7 = S[14] + S[15];
                float b0 = a0 + a1, b1 = a2 + a3, b2 = a4 + a5, b3 = a6 + a7;
                lsum += (b0 + b1) + (b2 + b3);
            }

            unsigned pk[4][2];
#pragma unroll
            for (int a = 0; a < 4; ++a)
#pragma unroll
                for (int u = 0; u < 2; ++u)
                    pk[a][u] = cvt_pk_bf16(S[4 * a + 2 * u], S[4 * a + 2 * u + 1]);

#pragma unroll
            for (int ks = 0; ks < 2; ++ks) {
                unsigned u0 = pk[2 * ks][0], u2 = pk[2 * ks + 1][0];
                unsigned u1 = pk[2 * ks][1], u3 = pk[2 * ks + 1][1];
                asm("v_permlane32_swap_b32 %0, %1" : "+v"(u0), "+v"(u2));
                asm("v_permlane32_swap_b32 %0, %1" : "+v"(u1), "+v"(u3));
                union { bf16x8 v; unsigned u[4]; } pf;
                pf.u[0] = u0; pf.u[1] = u1; pf.u[2] = u2; pf.u[3] = u3;
                O0 = MFMA32(vf[ks], pf.v, O0);
                O1 = MFMA32(vf[2 + ks], pf.v, O1);
            }
        }

        if (jt < 15) {
            // buf[cur^1]'s last readers finished before the PREVIOUS barrier:
            // one barrier per iteration suffices.
            *(int4*)&Klds[cur ^ 1][krow][kcol] = kreg;
            *(int4*)&Vlds[cur ^ 1][vrow][vcol] = vreg0;
            *(int4*)&Vlds[cur ^ 1][vrow + 32][vcol] = vreg1;
            __syncthreads();
            cur ^= 1;
        }
    }

    lsum += __shfl_xor(lsum, 32);
    float inv = 1.0f / lsum;

    // per-wave epilogue: GELU in regs, transpose via private tb slab, 16B stores
    short (*tw)[68] = tb[wave];
#pragma unroll
    for (int dn = 0; dn < 2; ++dn)
#pragma unroll
        for (int a = 0; a < 4; ++a) {
            short4 w;
#pragma unroll
            for (int bb = 0; bb < 4; ++bb) {
                float v = (dn ? O1[4 * a + bb] : O0[4 * a + bb]) * inv;
                v = 0.5f * v * (1.f + erff(v * 0.70710678118654752f));  // exact GELU
                ((short*)&w)[bb] = f2bf(v);
            }
            *(short4*)&tw[ql][dn * 32 + 8 * a + 4 * hi] = w;
        }
#pragma unroll
    for (int c = 0; c < 4; ++c) {
        int4 val = *(const int4*)&tw[ql][(hi * 4 + c) * 8];
        *(int4*)(Xg + ((size_t)b * NSEQ + q0 + ql) * 512 + h * 64 + (hi * 4 + c) * 8) = val;
    }
}

// ---------------- K4: output projection + bias + BN (128x64, global_load_lds staging) ----------------
__global__ __launch_bounds__(256) void out_gemm(
    const short* __restrict__ Xg, const short* __restrict__ Wo,
    const float* __restrict__ bo, const float* __restrict__ og, const float* __restrict__ ob,
    const float* __restrict__ om, const float* __restrict__ ov,
    float* __restrict__ out)
{
    __shared__ short At[128][32];
    __shared__ short Bt[64][32];
    int mt = blockIdx.x, nt = blockIdx.y;
    int t = threadIdx.x, wave = t >> 6, lane = t & 63;
    int wr = wave >> 1, wc = wave & 1, lr = lane & 15, lg = lane >> 4;
    int row0 = mt * 128, o0 = nt * 64;

    int srow = lane >> 2, scol = (lane & 3) * 8;
    int rA0 = (wave * 2) * 16 + srow, rA1 = (wave * 2 + 1) * 16 + srow;
    int rB  = wave * 16 + srow;
    short* lA0 = &At[0][0] + (wave * 2) * 512;
    short* lA1 = &At[0][0] + (wave * 2 + 1) * 512;
    short* lB  = &Bt[0][0] + wave * 512;

    f32x4 acc[4][2];
#pragma unroll
    for (int m = 0; m < 4; ++m)
#pragma unroll
        for (int n = 0; n < 2; ++n) acc[m][n] = (f32x4){0.f, 0.f, 0.f, 0.f};

    for (int k0 = 0; k0 < 512; k0 += 32) {
        gload16(Xg + (size_t)(row0 + rA0) * 512 + k0 + scol, lA0);
        gload16(Xg + (size_t)(row0 + rA1) * 512 + k0 + scol, lA1);
        gload16(Wo + (size_t)(o0 + rB) * 512 + k0 + scol, lB);
        __syncthreads();
        bf16x8 af[4], bfr[2];
#pragma unroll
        for (int m = 0; m < 4; ++m) af[m] = *(const bf16x8*)&At[wr * 64 + m * 16 + lr][lg * 8];
#pragma unroll
        for (int n = 0; n < 2; ++n) bfr[n] = *(const bf16x8*)&Bt[wc * 32 + n * 16 + lr][lg * 8];
#pragma unroll
        for (int m = 0; m < 4; ++m)
#pragma unroll
            for (int n = 0; n < 2; ++n)
                acc[m][n] = MFMA16(af[m], bfr[n], acc[m][n]);
        __syncthreads();
    }

    int b = row0 >> 10;
    int pbase = row0 & 1023;
#pragma unroll
    for (int n = 0; n < 2; ++n) {
        int o = o0 + wc * 32 + n * 16 + lr;
        float inv = og[o] * rsqrtf(ov[o] + 1e-5f);
        float off = bo[o] * inv + ob[o] - om[o] * inv;
        float* dst = out + ((size_t)b * 256 + o) * 1024 + pbase;
#pragma unroll
        for (int m = 0; m < 4; ++m)
#pragma unroll
            for (int r = 0; r < 4; ++r) {
                int p = wr * 64 + m * 16 + lg * 4 + r;
                dst[p] = acc[m][n][r] * inv + off;
            }
    }
}

// ---------------- launch ----------------
extern "C" void kernel_launch(void* const* d_in, const int* in_sizes, int n_in,
                              void* d_out, int out_size, void* d_ws, size_t ws_size,
                              hipStream_t stream) {
    const float* x     = (const float*)d_in[0];
    const float* wq    = (const float*)d_in[1];
    const float* qgam  = (const float*)d_in[2];
    const float* qbet  = (const float*)d_in[3];
    const float* qmu   = (const float*)d_in[4];
    const float* qvar  = (const float*)d_in[5];
    const float* wk    = (const float*)d_in[6];
    const float* kgam  = (const float*)d_in[7];
    const float* kbet  = (const float*)d_in[8];
    const float* kmu   = (const float*)d_in[9];
    const float* kvar  = (const float*)d_in[10];
    const float* wv    = (const float*)d_in[11];
    const float* vgam  = (const float*)d_in[12];
    const float* vbet  = (const float*)d_in[13];
    const float* vmu   = (const float*)d_in[14];
    const float* vvar  = (const float*)d_in[15];
    const float* wo    = (const float*)d_in[16];
    const float* bo    = (const float*)d_in[17];
    const float* ogam  = (const float*)d_in[18];
    const float* obet  = (const float*)d_in[19];
    const float* omu   = (const float*)d_in[20];
    const float* ovar  = (const float*)d_in[21];
    const float* pos_emb = (const float*)d_in[22];
    // d_in[23] pos_indices: recomputed analytically in-kernel

    char* ws = (char*)d_ws;
    short* Wqkv = (short*)(ws + 0);          // 524288
    float* Bqkv = (float*)(ws + 524288);     // 4096
    short* Wo   = (short*)(ws + 528384);     // 262144
    short* Xt   = (short*)(ws + 790528);     // 4 MB
    short* Qd   = (short*)(ws + 4984832);    // 4 MB
    short* Kd   = (short*)(ws + 9179136);    // 4 MB
    short* Vtd  = (short*)(ws + 13373440);   // 8 MB
    short* Xg   = (short*)(ws + 21762048);   // 8 MB (end 30150656)

    prep_trans_kernel<<<1792, 256, 0, stream>>>(x, Xt,
                                                wq, qgam, qbet, qmu, qvar,
                                                wk, kgam, kbet, kmu, kvar,
                                                wv, vgam, vbet, vmu, vvar,
                                                wo, Wqkv, Bqkv, Wo);
    qkv_gemm<<<dim3(8, 8, NB), 256, 0, stream>>>(Xt, Wqkv, Bqkv, Qd, Kd, Vtd);
    attn_kernel<<<512, 256, 0, stream>>>(Qd, Kd, Vtd, pos_emb, Xg);
    out_gemm<<<dim3(64, 4), 256, 0, stream>>>(Xg, Wo, bo, ogam, obet, omu, ovar, (float*)d_out);
}

// Round 16
// 72.865 us; speedup vs baseline: 1.0443x; 1.0034x over previous
//
#include <hip/hip_runtime.h>
#include <math.h>

#define NB 8
#define NHEADS 8
#define NDK 32
#define NDV 64
#define NSEQ 1024
#define NCIN 256

typedef __attribute__((ext_vector_type(8))) short bf16x8;
typedef __attribute__((ext_vector_type(4))) float f32x4;
typedef __attribute__((ext_vector_type(16))) float f32x16;

#define MFMA16(A, B, C) __builtin_amdgcn_mfma_f32_16x16x32_bf16(A, B, C, 0, 0, 0)
#define MFMA32(A, B, C) __builtin_amdgcn_mfma_f32_32x32x16_bf16(A, B, C, 0, 0, 0)

// log2e folded constants: logits2 = (q*SC2)·k + pe*PE2, SC2 pre-folded into Q weights
#define SC2 0.2550347873f
#define PE2 8.1611156f

__device__ __forceinline__ short f2bf(float f) {
    union { float f; unsigned u; } v; v.f = f;
    unsigned r = v.u + 0x7FFFu + ((v.u >> 16) & 1u);
    return (short)(r >> 16);
}

__device__ __forceinline__ unsigned cvt_pk_bf16(float lo, float hi) {
    unsigned r;
    asm("v_cvt_pk_bf16_f32 %0, %1, %2" : "=v"(r) : "v"(lo), "v"(hi));
    return r;
}

// async global->LDS, 16B/lane. LDS dest must be wave-uniform base (HW adds lane*16).
__device__ __forceinline__ void gload16(const short* g, short* l) {
    __builtin_amdgcn_global_load_lds(
        (const __attribute__((address_space(1))) void*)g,
        (__attribute__((address_space(3))) void*)l, 16, 0, 0);
}

// ---------------- K0: fused {x transpose} + {BN fold + bf16 convert} ----------------
__global__ __launch_bounds__(256) void prep_trans_kernel(
    const float* __restrict__ x, short* __restrict__ Xt,
    const float* __restrict__ wq, const float* __restrict__ qg, const float* __restrict__ qb,
    const float* __restrict__ qm, const float* __restrict__ qv,
    const float* __restrict__ wk, const float* __restrict__ kg, const float* __restrict__ kb,
    const float* __restrict__ km, const float* __restrict__ kv,
    const float* __restrict__ wv, const float* __restrict__ vg, const float* __restrict__ vb,
    const float* __restrict__ vm, const float* __restrict__ vv,
    const float* __restrict__ wo,
    short* __restrict__ Wqkv, float* __restrict__ Bqkv, short* __restrict__ Wo)
{
    __shared__ float tile[64][65];
    int bid = blockIdx.x, t = threadIdx.x;
    if (bid < 512) {
        int p0 = (bid & 15) * 64, c0 = ((bid >> 4) & 3) * 64, b = bid >> 6;
        int tp = t & 63, tr = t >> 6;
        const float* xb = x + ((size_t)b * NCIN + c0) * NSEQ + p0;
#pragma unroll
        for (int i = 0; i < 16; ++i) {
            int cl = tr * 16 + i;
            tile[cl][tp] = xb[(size_t)cl * NSEQ + tp];
        }
        __syncthreads();
        short* xt = Xt + ((size_t)b * NSEQ + p0) * NCIN + c0;
#pragma unroll
        for (int i = 0; i < 16; ++i) {
            int pl = tr * 16 + i;
            xt[(size_t)pl * NCIN + tp] = f2bf(tile[tp][pl]);
        }
    } else {
        int row = bid - 512;
        if (row < 1024) {
            const float *w, *g, *be, *mu, *va; int o; float sc;
            if (row < 256)      { w = wq; o = row;       g = qg; be = qb; mu = qm; va = qv; sc = SC2; }
            else if (row < 512) { w = wk; o = row - 256; g = kg; be = kb; mu = km; va = kv; sc = 1.f; }
            else                { w = wv; o = row - 512; g = vg; be = vb; mu = vm; va = vv; sc = 1.f; }
            float inv = g[o] * rsqrtf(va[o] + 1e-5f) * sc;
            Wqkv[row * NCIN + t] = f2bf(w[o * NCIN + t] * inv);
            if (t == 0) Bqkv[row] = (be[o] - mu[o] * (g[o] * rsqrtf(va[o] + 1e-5f))) * sc;
        } else {
            int o = row - 1024;
            Wo[o * 512 + t]       = f2bf(wo[o * 512 + t]);
            Wo[o * 512 + 256 + t] = f2bf(wo[o * 512 + 256 + t]);
        }
    }
}

// ---------------- K2: QKV projection GEMM (global_load_lds staging) ----------------
__global__ __launch_bounds__(256) void qkv_gemm(
    const short* __restrict__ Xt, const short* __restrict__ Wqkv, const float* __restrict__ Bqkv,
    short* __restrict__ Qo, short* __restrict__ Ko, short* __restrict__ Vto)
{
    __shared__ short At[128][32];
    __shared__ short Bt[128][32];
    int b = blockIdx.z, p0 = blockIdx.x * 128, o0 = blockIdx.y * 128;
    int t = threadIdx.x, wave = t >> 6, lane = t & 63;
    int wr = wave >> 1, wc = wave & 1, lr = lane & 15, lg = lane >> 4;

    const short* Abase = Xt + ((size_t)b * NSEQ + p0) * NCIN;
    const short* Bbase = Wqkv + (size_t)o0 * NCIN;

    int srow = lane >> 2, scol = (lane & 3) * 8;
    int r0 = (wave * 2) * 16 + srow, r1 = (wave * 2 + 1) * 16 + srow;
    short* lA0 = &At[0][0] + (wave * 2) * 512;
    short* lA1 = &At[0][0] + (wave * 2 + 1) * 512;
    short* lB0 = &Bt[0][0] + (wave * 2) * 512;
    short* lB1 = &Bt[0][0] + (wave * 2 + 1) * 512;

    f32x4 acc[4][4];
#pragma unroll
    for (int m = 0; m < 4; ++m)
#pragma unroll
        for (int n = 0; n < 4; ++n) acc[m][n] = (f32x4){0.f, 0.f, 0.f, 0.f};

    for (int k0 = 0; k0 < NCIN; k0 += 32) {
        gload16(Abase + (size_t)r0 * NCIN + k0 + scol, lA0);
        gload16(Abase + (size_t)r1 * NCIN + k0 + scol, lA1);
        gload16(Bbase + (size_t)r0 * NCIN + k0 + scol, lB0);
        gload16(Bbase + (size_t)r1 * NCIN + k0 + scol, lB1);
        __syncthreads();
        bf16x8 af[4], bfr[4];
#pragma unroll
        for (int m = 0; m < 4; ++m) af[m] = *(const bf16x8*)&At[wr * 64 + m * 16 + lr][lg * 8];
#pragma unroll
        for (int n = 0; n < 4; ++n) bfr[n] = *(const bf16x8*)&Bt[wc * 64 + n * 16 + lr][lg * 8];
#pragma unroll
        for (int m = 0; m < 4; ++m)
#pragma unroll
            for (int n = 0; n < 4; ++n)
                acc[m][n] = MFMA16(af[m], bfr[n], acc[m][n]);
        __syncthreads();
    }

#pragma unroll
    for (int n = 0; n < 4; ++n) {
        int o = o0 + wc * 64 + n * 16 + lr;
        float bias = Bqkv[o];
#pragma unroll
        for (int m = 0; m < 4; ++m) {
            int pr = p0 + wr * 64 + m * 16 + lg * 4;
#pragma unroll
            for (int r = 0; r < 4; ++r) {
                float y = acc[m][n][r] + bias;
                short vv = f2bf(y);
                int p = pr + r;
                if (o < 256) {
                    int hh = o >> 5, d = o & 31;
                    Qo[(((size_t)b * NHEADS + hh) * NSEQ + p) * NDK + d] = vv;
                } else if (o < 512) {
                    int oo = o - 256, hh = oo >> 5, d = oo & 31;
                    Ko[(((size_t)b * NHEADS + hh) * NSEQ + p) * NDK + d] = vv;
                } else {
                    int oo = o - 512, hh = oo >> 6, d = oo & 63;
                    Vto[(((size_t)b * NHEADS + hh) * NDV + d) * NSEQ + p] = vv;
                }
            }
        }
    }
}

// ---------------- K3: flash attention + GELU (lsum on the MFMA pipe) ----------------
// R15 structure; the softmax denominator is now computed by one extra
// MFMA32(ones, pf, Osum) per k-slice: Osum[r] = sum_j P[j][q] for the lane's
// q — replaces the 15-add VALU tree, the loop-carried lsum scalar, and the
// final cross-half shuffle with work on the ~10%-utilized matrix pipe.
// Denominator now sums bf16-rounded P, CONSISTENT with the PV numerator.
__global__ __launch_bounds__(256) void attn_kernel(
    const short* __restrict__ Q, const short* __restrict__ K, const short* __restrict__ Vt,
    const float* __restrict__ pos_emb, short* __restrict__ Xg)
{
    __shared__ float peR[32][64];
    __shared__ short Klds[2][64][36];    // [buf][key][d]
    __shared__ short Vlds[2][64][68];    // [buf][d][j]
    __shared__ short tb[4][32][68];      // per-wave epilogue transpose

    int bid = blockIdx.x;
    int h = bid & 7;                     // head per XCD: K/V set 1.5MB/XCD (L2-fit)
    int qt = (bid >> 3) & 7;
    int b = bid >> 6;
    int t = threadIdx.x, wave = t >> 6, l = t & 63, ql = l & 31, hi = l >> 5;

    {   // build reversed bias table: peR[dr][y] = pe[dr*32 + |31-y|] * PE2
        int dr = t >> 3, y0 = (t & 7) * 8;
#pragma unroll
        for (int k = 0; k < 8; ++k) {
            int y = y0 + k;
            if (y < 63) {
                int d = 31 - y; d = d < 0 ? -d : d;
                peR[dr][y] = pos_emb[(dr * 32 + d) * NHEADS + h] * PE2;
            }
        }
    }

    size_t bh = (size_t)b * NHEADS + h;
    const short* Qb = Q + bh * NSEQ * NDK;
    const short* Kb = K + bh * NSEQ * NDK;
    const short* Vb = Vt + bh * NDV * NSEQ;

    int q0 = qt * 128 + wave * 32;
    int iq = q0 + ql;
    int qr = iq >> 5;
    int pebase = 31 - ql + 4 * hi;

    bf16x8 qf0 = *(const bf16x8*)(Qb + (size_t)iq * NDK + hi * 8);
    bf16x8 qf1 = *(const bf16x8*)(Qb + (size_t)iq * NDK + 16 + hi * 8);

    int krow = t >> 2, kcol = (t & 3) * 8;
    int vrow = t >> 3, vcol = (t & 7) * 8;

    // all-ones A-fragment (layout-independent: every element 1.0 bf16)
    union { unsigned u[4]; bf16x8 v; } oneu;
    oneu.u[0] = 0x3F803F80u; oneu.u[1] = 0x3F803F80u;
    oneu.u[2] = 0x3F803F80u; oneu.u[3] = 0x3F803F80u;

    // prologue: stage tile 0 into buf 0
    {
        int4 kreg  = *(const int4*)(Kb + (size_t)krow * NDK + kcol);
        int4 vreg0 = *(const int4*)(Vb + (size_t)vrow * NSEQ + vcol);
        int4 vreg1 = *(const int4*)(Vb + (size_t)(vrow + 32) * NSEQ + vcol);
        *(int4*)&Klds[0][krow][kcol] = kreg;
        *(int4*)&Vlds[0][vrow][vcol] = vreg0;
        *(int4*)&Vlds[0][vrow + 32][vcol] = vreg1;
    }
    __syncthreads();   // peR + tile 0 ready

    f32x16 O0, O1, Osum;
#pragma unroll
    for (int r = 0; r < 16; ++r) { O0[r] = 0.f; O1[r] = 0.f; Osum[r] = 0.f; }

    int cur = 0;
    for (int jt = 0; jt < 16; ++jt) {
        int4 kreg, vreg0, vreg1;
        if (jt < 15) {   // issue next-tile loads early; latency hides under compute
            int j0n = (jt + 1) * 64;
            kreg  = *(const int4*)(Kb + (size_t)(j0n + krow) * NDK + kcol);
            vreg0 = *(const int4*)(Vb + (size_t)vrow * NSEQ + j0n + vcol);
            vreg1 = *(const int4*)(Vb + (size_t)(vrow + 32) * NSEQ + j0n + vcol);
        }

#pragma unroll
        for (int s = 0; s < 2; ++s) {
            int jr = (jt * 64 + s * 32) >> 5;
            int drb = qr - jr; drb = drb < 0 ? -drb : drb;   // wave-uniform
            const float* per = &peR[drb][pebase];

            bf16x8 kf0 = *(const bf16x8*)&Klds[cur][s * 32 + ql][hi * 8];
            bf16x8 kf1 = *(const bf16x8*)&Klds[cur][s * 32 + ql][16 + hi * 8];

            // C-init = bias (S[r] needs per[jcr], jcr = (r&3)+8*(r>>2))
            f32x16 S;
#pragma unroll
            for (int a = 0; a < 4; ++a)
#pragma unroll
                for (int u = 0; u < 4; ++u)
                    S[4 * a + u] = per[8 * a + u];
            S = MFMA32(kf0, qf0, S);
            S = MFMA32(kf1, qf1, S);

            bf16x8 vf[4];
#pragma unroll
            for (int dn = 0; dn < 2; ++dn)
#pragma unroll
                for (int ks = 0; ks < 2; ++ks)
                    vf[dn * 2 + ks] = *(const bf16x8*)&Vlds[cur][dn * 32 + ql][s * 32 + ks * 16 + hi * 8];

            // P = exp2(logits2) directly (|logits2| << 127, shift-invariant)
#pragma unroll
            for (int r = 0; r < 16; ++r) S[r] = __builtin_amdgcn_exp2f(S[r]);

            unsigned pk[4][2];
#pragma unroll
            for (int a = 0; a < 4; ++a)
#pragma unroll
                for (int u = 0; u < 2; ++u)
                    pk[a][u] = cvt_pk_bf16(S[4 * a + 2 * u], S[4 * a + 2 * u + 1]);

#pragma unroll
            for (int ks = 0; ks < 2; ++ks) {
                unsigned u0 = pk[2 * ks][0], u2 = pk[2 * ks + 1][0];
                unsigned u1 = pk[2 * ks][1], u3 = pk[2 * ks + 1][1];
                asm("v_permlane32_swap_b32 %0, %1" : "+v"(u0), "+v"(u2));
                asm("v_permlane32_swap_b32 %0, %1" : "+v"(u1), "+v"(u3));
                union { bf16x8 v; unsigned u[4]; } pf;
                pf.u[0] = u0; pf.u[1] = u1; pf.u[2] = u2; pf.u[3] = u3;
                O0 = MFMA32(vf[ks], pf.v, O0);
                O1 = MFMA32(vf[2 + ks], pf.v, O1);
                Osum = MFMA32(oneu.v, pf.v, Osum);   // denominator on the matrix pipe
            }
        }

        if (jt < 15) {
            // buf[cur^1]'s last readers finished before the PREVIOUS barrier:
            // one barrier per iteration suffices.
            *(int4*)&Klds[cur ^ 1][krow][kcol] = kreg;
            *(int4*)&Vlds[cur ^ 1][vrow][vcol] = vreg0;
            *(int4*)&Vlds[cur ^ 1][vrow + 32][vcol] = vreg1;
            __syncthreads();
            cur ^= 1;
        }
    }

    // Osum[r][q] identical for all r (all-ones rows): lane-local total denominator
    float inv = 1.0f / Osum[0];

    // per-wave epilogue: GELU in regs, transpose via private tb slab, 16B stores
    short (*tw)[68] = tb[wave];
#pragma unroll
    for (int dn = 0; dn < 2; ++dn)
#pragma unroll
        for (int a = 0; a < 4; ++a) {
            short4 w;
#pragma unroll
            for (int bb = 0; bb < 4; ++bb) {
                float v = (dn ? O1[4 * a + bb] : O0[4 * a + bb]) * inv;
                v = 0.5f * v * (1.f + erff(v * 0.70710678118654752f));  // exact GELU
                ((short*)&w)[bb] = f2bf(v);
            }
            *(short4*)&tw[ql][dn * 32 + 8 * a + 4 * hi] = w;
        }
#pragma unroll
    for (int c = 0; c < 4; ++c) {
        int4 val = *(const int4*)&tw[ql][(hi * 4 + c) * 8];
        *(int4*)(Xg + ((size_t)b * NSEQ + q0 + ql) * 512 + h * 64 + (hi * 4 + c) * 8) = val;
    }
}

// ---------------- K4: output projection + bias + BN (128x64, global_load_lds staging) ----------------
__global__ __launch_bounds__(256) void out_gemm(
    const short* __restrict__ Xg, const short* __restrict__ Wo,
    const float* __restrict__ bo, const float* __restrict__ og, const float* __restrict__ ob,
    const float* __restrict__ om, const float* __restrict__ ov,
    float* __restrict__ out)
{
    __shared__ short At[128][32];
    __shared__ short Bt[64][32];
    int mt = blockIdx.x, nt = blockIdx.y;
    int t = threadIdx.x, wave = t >> 6, lane = t & 63;
    int wr = wave >> 1, wc = wave & 1, lr = lane & 15, lg = lane >> 4;
    int row0 = mt * 128, o0 = nt * 64;

    int srow = lane >> 2, scol = (lane & 3) * 8;
    int rA0 = (wave * 2) * 16 + srow, rA1 = (wave * 2 + 1) * 16 + srow;
    int rB  = wave * 16 + srow;
    short* lA0 = &At[0][0] + (wave * 2) * 512;
    short* lA1 = &At[0][0] + (wave * 2 + 1) * 512;
    short* lB  = &Bt[0][0] + wave * 512;

    f32x4 acc[4][2];
#pragma unroll
    for (int m = 0; m < 4; ++m)
#pragma unroll
        for (int n = 0; n < 2; ++n) acc[m][n] = (f32x4){0.f, 0.f, 0.f, 0.f};

    for (int k0 = 0; k0 < 512; k0 += 32) {
        gload16(Xg + (size_t)(row0 + rA0) * 512 + k0 + scol, lA0);
        gload16(Xg + (size_t)(row0 + rA1) * 512 + k0 + scol, lA1);
        gload16(Wo + (size_t)(o0 + rB) * 512 + k0 + scol, lB);
        __syncthreads();
        bf16x8 af[4], bfr[2];
#pragma unroll
        for (int m = 0; m < 4; ++m) af[m] = *(const bf16x8*)&At[wr * 64 + m * 16 + lr][lg * 8];
#pragma unroll
        for (int n = 0; n < 2; ++n) bfr[n] = *(const bf16x8*)&Bt[wc * 32 + n * 16 + lr][lg * 8];
#pragma unroll
        for (int m = 0; m < 4; ++m)
#pragma unroll
            for (int n = 0; n < 2; ++n)
                acc[m][n] = MFMA16(af[m], bfr[n], acc[m][n]);
        __syncthreads();
    }

    int b = row0 >> 10;
    int pbase = row0 & 1023;
#pragma unroll
    for (int n = 0; n < 2; ++n) {
        int o = o0 + wc * 32 + n * 16 + lr;
        float inv = og[o] * rsqrtf(ov[o] + 1e-5f);
        float off = bo[o] * inv + ob[o] - om[o] * inv;
        float* dst = out + ((size_t)b * 256 + o) * 1024 + pbase;
#pragma unroll
        for (int m = 0; m < 4; ++m)
#pragma unroll
            for (int r = 0; r < 4; ++r) {
                int p = wr * 64 + m * 16 + lg * 4 + r;
                dst[p] = acc[m][n][r] * inv + off;
            }
    }
}

// ---------------- launch ----------------
extern "C" void kernel_launch(void* const* d_in, const int* in_sizes, int n_in,
                              void* d_out, int out_size, void* d_ws, size_t ws_size,
                              hipStream_t stream) {
    const float* x     = (const float*)d_in[0];
    const float* wq    = (const float*)d_in[1];
    const float* qgam  = (const float*)d_in[2];
    const float* qbet  = (const float*)d_in[3];
    const float* qmu   = (const float*)d_in[4];
    const float* qvar  = (const float*)d_in[5];
    const float* wk    = (const float*)d_in[6];
    const float* kgam  = (const float*)d_in[7];
    const float* kbet  = (const float*)d_in[8];
    const float* kmu   = (const float*)d_in[9];
    const float* kvar  = (const float*)d_in[10];
    const float* wv    = (const float*)d_in[11];
    const float* vgam  = (const float*)d_in[12];
    const float* vbet  = (const float*)d_in[13];
    const float* vmu   = (const float*)d_in[14];
    const float* vvar  = (const float*)d_in[15];
    const float* wo    = (const float*)d_in[16];
    const float* bo    = (const float*)d_in[17];
    const float* ogam  = (const float*)d_in[18];
    const float* obet  = (const float*)d_in[19];
    const float* omu   = (const float*)d_in[20];
    const float* ovar  = (const float*)d_in[21];
    const float* pos_emb = (const float*)d_in[22];
    // d_in[23] pos_indices: recomputed analytically in-kernel

    char* ws = (char*)d_ws;
    short* Wqkv = (short*)(ws + 0);          // 524288
    float* Bqkv = (float*)(ws + 524288);     // 4096
    short* Wo   = (short*)(ws + 528384);     // 262144
    short* Xt   = (short*)(ws + 790528);     // 4 MB
    short* Qd   = (short*)(ws + 4984832);    // 4 MB
    short* Kd   = (short*)(ws + 9179136);    // 4 MB
    short* Vtd  = (short*)(ws + 13373440);   // 8 MB
    short* Xg   = (short*)(ws + 21762048);   // 8 MB (end 30150656)

    prep_trans_kernel<<<1792, 256, 0, stream>>>(x, Xt,
                                                wq, qgam, qbet, qmu, qvar,
                                                wk, kgam, kbet, kmu, kvar,
                                                wv, vgam, vbet, vmu, vvar,
                                                wo, Wqkv, Bqkv, Wo);
    qkv_gemm<<<dim3(8, 8, NB), 256, 0, stream>>>(Xt, Wqkv, Bqkv, Qd, Kd, Vtd);
    attn_kernel<<<512, 256, 0, stream>>>(Qd, Kd, Vtd, pos_emb, Xg);
    out_gemm<<<dim3(64, 4), 256, 0, stream>>>(Xg, Wo, bo, ogam, obet, omu, ovar, (float*)d_out);
}

// Round 17
// 60.120 us; speedup vs baseline: 1.2657x; 1.2120x over previous
//
#include <hip/hip_runtime.h>
#include <math.h>

#define NB 8
#define NHEADS 8
#define NDK 32
#define NDV 64
#define NSEQ 1024
#define NCIN 256

typedef __attribute__((ext_vector_type(8))) short bf16x8;
typedef __attribute__((ext_vector_type(4))) float f32x4;
typedef __attribute__((ext_vector_type(16))) float f32x16;

#define MFMA16(A, B, C) __builtin_amdgcn_mfma_f32_16x16x32_bf16(A, B, C, 0, 0, 0)
#define MFMA32(A, B, C) __builtin_amdgcn_mfma_f32_32x32x16_bf16(A, B, C, 0, 0, 0)

// log2e folded constants: logits2 = (q*SC2)·k + pe*PE2, SC2 pre-folded into Q weights
#define SC2 0.2550347873f
#define PE2 8.1611156f

__device__ __forceinline__ short f2bf(float f) {
    union { float f; unsigned u; } v; v.f = f;
    unsigned r = v.u + 0x7FFFu + ((v.u >> 16) & 1u);
    return (short)(r >> 16);
}

__device__ __forceinline__ unsigned cvt_pk_bf16(float lo, float hi) {
    unsigned r;
    asm("v_cvt_pk_bf16_f32 %0, %1, %2" : "=v"(r) : "v"(lo), "v"(hi));
    return r;
}

// async global->LDS, 16B/lane. LDS dest must be wave-uniform base (HW adds lane*16).
__device__ __forceinline__ void gload16(const short* g, short* l) {
    __builtin_amdgcn_global_load_lds(
        (const __attribute__((address_space(1))) void*)g,
        (__attribute__((address_space(3))) void*)l, 16, 0, 0);
}

// ---------------- K0: fused {x transpose} + {BN fold + bf16 convert} ----------------
__global__ __launch_bounds__(256) void prep_trans_kernel(
    const float* __restrict__ x, short* __restrict__ Xt,
    const float* __restrict__ wq, const float* __restrict__ qg, const float* __restrict__ qb,
    const float* __restrict__ qm, const float* __restrict__ qv,
    const float* __restrict__ wk, const float* __restrict__ kg, const float* __restrict__ kb,
    const float* __restrict__ km, const float* __restrict__ kv,
    const float* __restrict__ wv, const float* __restrict__ vg, const float* __restrict__ vb,
    const float* __restrict__ vm, const float* __restrict__ vv,
    const float* __restrict__ wo,
    short* __restrict__ Wqkv, float* __restrict__ Bqkv, short* __restrict__ Wo)
{
    __shared__ float tile[64][65];
    int bid = blockIdx.x, t = threadIdx.x;
    if (bid < 512) {
        int p0 = (bid & 15) * 64, c0 = ((bid >> 4) & 3) * 64, b = bid >> 6;
        int tp = t & 63, tr = t >> 6;
        const float* xb = x + ((size_t)b * NCIN + c0) * NSEQ + p0;
#pragma unroll
        for (int i = 0; i < 16; ++i) {
            int cl = tr * 16 + i;
            tile[cl][tp] = xb[(size_t)cl * NSEQ + tp];
        }
        __syncthreads();
        short* xt = Xt + ((size_t)b * NSEQ + p0) * NCIN + c0;
#pragma unroll
        for (int i = 0; i < 16; ++i) {
            int pl = tr * 16 + i;
            xt[(size_t)pl * NCIN + tp] = f2bf(tile[tp][pl]);
        }
    } else {
        int row = bid - 512;
        if (row < 1024) {
            const float *w, *g, *be, *mu, *va; int o; float sc;
            if (row < 256)      { w = wq; o = row;       g = qg; be = qb; mu = qm; va = qv; sc = SC2; }
            else if (row < 512) { w = wk; o = row - 256; g = kg; be = kb; mu = km; va = kv; sc = 1.f; }
            else                { w = wv; o = row - 512; g = vg; be = vb; mu = vm; va = vv; sc = 1.f; }
            float inv = g[o] * rsqrtf(va[o] + 1e-5f) * sc;
            Wqkv[row * NCIN + t] = f2bf(w[o * NCIN + t] * inv);
            if (t == 0) Bqkv[row] = (be[o] - mu[o] * (g[o] * rsqrtf(va[o] + 1e-5f))) * sc;
        } else {
            int o = row - 1024;
            Wo[o * 512 + t]       = f2bf(wo[o * 512 + t]);
            Wo[o * 512 + 256 + t] = f2bf(wo[o * 512 + 256 + t]);
        }
    }
}

// ---------------- K2: QKV projection GEMM (global_load_lds staging) ----------------
// V-region blocks (o0 >= 512) transpose the accumulator through a per-wave LDS
// slab and store coalesced 16B runs (V layout is (b,h,d,n): direct stores were
// 2B scatters at 2KB stride = ~16 lines per store instruction).
__global__ __launch_bounds__(256) void qkv_gemm(
    const short* __restrict__ Xt, const short* __restrict__ Wqkv, const float* __restrict__ Bqkv,
    short* __restrict__ Qo, short* __restrict__ Ko, short* __restrict__ Vto)
{
    __shared__ short At[128][32];
    __shared__ short Bt[128][32];
    __shared__ short vtb[4][64][72];   // per-wave V transpose slab (72: 2-way-free pad)
    int b = blockIdx.z, p0 = blockIdx.x * 128, o0 = blockIdx.y * 128;
    int t = threadIdx.x, wave = t >> 6, lane = t & 63;
    int wr = wave >> 1, wc = wave & 1, lr = lane & 15, lg = lane >> 4;

    const short* Abase = Xt + ((size_t)b * NSEQ + p0) * NCIN;
    const short* Bbase = Wqkv + (size_t)o0 * NCIN;

    int srow = lane >> 2, scol = (lane & 3) * 8;
    int r0 = (wave * 2) * 16 + srow, r1 = (wave * 2 + 1) * 16 + srow;
    short* lA0 = &At[0][0] + (wave * 2) * 512;
    short* lA1 = &At[0][0] + (wave * 2 + 1) * 512;
    short* lB0 = &Bt[0][0] + (wave * 2) * 512;
    short* lB1 = &Bt[0][0] + (wave * 2 + 1) * 512;

    f32x4 acc[4][4];
#pragma unroll
    for (int m = 0; m < 4; ++m)
#pragma unroll
        for (int n = 0; n < 4; ++n) acc[m][n] = (f32x4){0.f, 0.f, 0.f, 0.f};

    for (int k0 = 0; k0 < NCIN; k0 += 32) {
        gload16(Abase + (size_t)r0 * NCIN + k0 + scol, lA0);
        gload16(Abase + (size_t)r1 * NCIN + k0 + scol, lA1);
        gload16(Bbase + (size_t)r0 * NCIN + k0 + scol, lB0);
        gload16(Bbase + (size_t)r1 * NCIN + k0 + scol, lB1);
        __syncthreads();
        bf16x8 af[4], bfr[4];
#pragma unroll
        for (int m = 0; m < 4; ++m) af[m] = *(const bf16x8*)&At[wr * 64 + m * 16 + lr][lg * 8];
#pragma unroll
        for (int n = 0; n < 4; ++n) bfr[n] = *(const bf16x8*)&Bt[wc * 64 + n * 16 + lr][lg * 8];
#pragma unroll
        for (int m = 0; m < 4; ++m)
#pragma unroll
            for (int n = 0; n < 4; ++n)
                acc[m][n] = MFMA16(af[m], bfr[n], acc[m][n]);
        __syncthreads();
    }

    if (o0 >= 512) {
        // ---- V blocks: per-wave LDS transpose -> coalesced stores ----
        int hh = ((o0 - 512) >> 6) + wc;           // wave's head
        short (*tw)[72] = vtb[wave];
#pragma unroll
        for (int n = 0; n < 4; ++n) {
            float bias = Bqkv[o0 + wc * 64 + n * 16 + lr];
#pragma unroll
            for (int m = 0; m < 4; ++m)
#pragma unroll
                for (int r = 0; r < 4; ++r)
                    tw[n * 16 + lr][m * 16 + lg * 4 + r] = f2bf(acc[m][n][r] + bias);
        }
        // wave-private slab: compiler inserts lgkmcnt before dependent reads
        short* vdst = Vto + (((size_t)b * NHEADS + hh) * NDV) * NSEQ + p0 + wr * 64 + (lane & 7) * 8;
#pragma unroll
        for (int k = 0; k < 8; ++k) {
            int d = (lane >> 3) + 8 * k;
            int4 v = *(const int4*)&tw[d][(lane & 7) * 8];
            *(int4*)(vdst + (size_t)d * NSEQ) = v;
        }
    } else {
        // ---- Q/K blocks: direct stores (32B-chunked, acceptable) ----
#pragma unroll
        for (int n = 0; n < 4; ++n) {
            int o = o0 + wc * 64 + n * 16 + lr;
            float bias = Bqkv[o];
#pragma unroll
            for (int m = 0; m < 4; ++m) {
                int pr = p0 + wr * 64 + m * 16 + lg * 4;
#pragma unroll
                for (int r = 0; r < 4; ++r) {
                    float y = acc[m][n][r] + bias;
                    short vv = f2bf(y);
                    int p = pr + r;
                    if (o < 256) {
                        int hh = o >> 5, d = o & 31;
                        Qo[(((size_t)b * NHEADS + hh) * NSEQ + p) * NDK + d] = vv;
                    } else {
                        int oo = o - 256, hh = oo >> 5, d = oo & 31;
                        Ko[(((size_t)b * NHEADS + hh) * NSEQ + p) * NDK + d] = vv;
                    }
                }
            }
        }
    }
}

// ---------------- K3: flash attention + GELU (R16 frozen: lsum on the MFMA pipe) ----------------
__global__ __launch_bounds__(256) void attn_kernel(
    const short* __restrict__ Q, const short* __restrict__ K, const short* __restrict__ Vt,
    const float* __restrict__ pos_emb, short* __restrict__ Xg)
{
    __shared__ float peR[32][64];
    __shared__ short Klds[2][64][36];    // [buf][key][d]
    __shared__ short Vlds[2][64][68];    // [buf][d][j]
    __shared__ short tb[4][32][68];      // per-wave epilogue transpose

    int bid = blockIdx.x;
    int h = bid & 7;                     // head per XCD: K/V set 1.5MB/XCD (L2-fit)
    int qt = (bid >> 3) & 7;
    int b = bid >> 6;
    int t = threadIdx.x, wave = t >> 6, l = t & 63, ql = l & 31, hi = l >> 5;

    {   // build reversed bias table: peR[dr][y] = pe[dr*32 + |31-y|] * PE2
        int dr = t >> 3, y0 = (t & 7) * 8;
#pragma unroll
        for (int k = 0; k < 8; ++k) {
            int y = y0 + k;
            if (y < 63) {
                int d = 31 - y; d = d < 0 ? -d : d;
                peR[dr][y] = pos_emb[(dr * 32 + d) * NHEADS + h] * PE2;
            }
        }
    }

    size_t bh = (size_t)b * NHEADS + h;
    const short* Qb = Q + bh * NSEQ * NDK;
    const short* Kb = K + bh * NSEQ * NDK;
    const short* Vb = Vt + bh * NDV * NSEQ;

    int q0 = qt * 128 + wave * 32;
    int iq = q0 + ql;
    int qr = iq >> 5;
    int pebase = 31 - ql + 4 * hi;

    bf16x8 qf0 = *(const bf16x8*)(Qb + (size_t)iq * NDK + hi * 8);
    bf16x8 qf1 = *(const bf16x8*)(Qb + (size_t)iq * NDK + 16 + hi * 8);

    int krow = t >> 2, kcol = (t & 3) * 8;
    int vrow = t >> 3, vcol = (t & 7) * 8;

    // all-ones A-fragment (layout-independent: every element 1.0 bf16)
    union { unsigned u[4]; bf16x8 v; } oneu;
    oneu.u[0] = 0x3F803F80u; oneu.u[1] = 0x3F803F80u;
    oneu.u[2] = 0x3F803F80u; oneu.u[3] = 0x3F803F80u;

    // prologue: stage tile 0 into buf 0
    {
        int4 kreg  = *(const int4*)(Kb + (size_t)krow * NDK + kcol);
        int4 vreg0 = *(const int4*)(Vb + (size_t)vrow * NSEQ + vcol);
        int4 vreg1 = *(const int4*)(Vb + (size_t)(vrow + 32) * NSEQ + vcol);
        *(int4*)&Klds[0][krow][kcol] = kreg;
        *(int4*)&Vlds[0][vrow][vcol] = vreg0;
        *(int4*)&Vlds[0][vrow + 32][vcol] = vreg1;
    }
    __syncthreads();   // peR + tile 0 ready

    f32x16 O0, O1, Osum;
#pragma unroll
    for (int r = 0; r < 16; ++r) { O0[r] = 0.f; O1[r] = 0.f; Osum[r] = 0.f; }

    int cur = 0;
    for (int jt = 0; jt < 16; ++jt) {
        int4 kreg, vreg0, vreg1;
        if (jt < 15) {   // issue next-tile loads early; latency hides under compute
            int j0n = (jt + 1) * 64;
            kreg  = *(const int4*)(Kb + (size_t)(j0n + krow) * NDK + kcol);
            vreg0 = *(const int4*)(Vb + (size_t)vrow * NSEQ + j0n + vcol);
            vreg1 = *(const int4*)(Vb + (size_t)(vrow + 32) * NSEQ + j0n + vcol);
        }

#pragma unroll
        for (int s = 0; s < 2; ++s) {
            int jr = (jt * 64 + s * 32) >> 5;
            int drb = qr - jr; drb = drb < 0 ? -drb : drb;   // wave-uniform
            const float* per = &peR[drb][pebase];

            bf16x8 kf0 = *(const bf16x8*)&Klds[cur][s * 32 + ql][hi * 8];
            bf16x8 kf1 = *(const bf16x8*)&Klds[cur][s * 32 + ql][16 + hi * 8];

            // C-init = bias (S[r] needs per[jcr], jcr = (r&3)+8*(r>>2))
            f32x16 S;
#pragma unroll
            for (int a = 0; a < 4; ++a)
#pragma unroll
                for (int u = 0; u < 4; ++u)
                    S[4 * a + u] = per[8 * a + u];
            S = MFMA32(kf0, qf0, S);
            S = MFMA32(kf1, qf1, S);

            bf16x8 vf[4];
#pragma unroll
            for (int dn = 0; dn < 2; ++dn)
#pragma unroll
                for (int ks = 0; ks < 2; ++ks)
                    vf[dn * 2 + ks] = *(const bf16x8*)&Vlds[cur][dn * 32 + ql][s * 32 + ks * 16 + hi * 8];

            // P = exp2(logits2) directly (|logits2| << 127, shift-invariant)
#pragma unroll
            for (int r = 0; r < 16; ++r) S[r] = __builtin_amdgcn_exp2f(S[r]);

            unsigned pk[4][2];
#pragma unroll
            for (int a = 0; a < 4; ++a)
#pragma unroll
                for (int u = 0; u < 2; ++u)
                    pk[a][u] = cvt_pk_bf16(S[4 * a + 2 * u], S[4 * a + 2 * u + 1]);

#pragma unroll
            for (int ks = 0; ks < 2; ++ks) {
                unsigned u0 = pk[2 * ks][0], u2 = pk[2 * ks + 1][0];
                unsigned u1 = pk[2 * ks][1], u3 = pk[2 * ks + 1][1];
                asm("v_permlane32_swap_b32 %0, %1" : "+v"(u0), "+v"(u2));
                asm("v_permlane32_swap_b32 %0, %1" : "+v"(u1), "+v"(u3));
                union { bf16x8 v; unsigned u[4]; } pf;
                pf.u[0] = u0; pf.u[1] = u1; pf.u[2] = u2; pf.u[3] = u3;
                O0 = MFMA32(vf[ks], pf.v, O0);
                O1 = MFMA32(vf[2 + ks], pf.v, O1);
                Osum = MFMA32(oneu.v, pf.v, Osum);   // denominator on the matrix pipe
            }
        }

        if (jt < 15) {
            // buf[cur^1]'s last readers finished before the PREVIOUS barrier:
            // one barrier per iteration suffices.
            *(int4*)&Klds[cur ^ 1][krow][kcol] = kreg;
            *(int4*)&Vlds[cur ^ 1][vrow][vcol] = vreg0;
            *(int4*)&Vlds[cur ^ 1][vrow + 32][vcol] = vreg1;
            __syncthreads();
            cur ^= 1;
        }
    }

    // Osum[r][q] identical for all r (all-ones rows): lane-local total denominator
    float inv = 1.0f / Osum[0];

    // per-wave epilogue: GELU in regs, transpose via private tb slab, 16B stores
    short (*tw)[68] = tb[wave];
#pragma unroll
    for (int dn = 0; dn < 2; ++dn)
#pragma unroll
        for (int a = 0; a < 4; ++a) {
            short4 w;
#pragma unroll
            for (int bb = 0; bb < 4; ++bb) {
                float v = (dn ? O1[4 * a + bb] : O0[4 * a + bb]) * inv;
                v = 0.5f * v * (1.f + erff(v * 0.70710678118654752f));  // exact GELU
                ((short*)&w)[bb] = f2bf(v);
            }
            *(short4*)&tw[ql][dn * 32 + 8 * a + 4 * hi] = w;
        }
#pragma unroll
    for (int c = 0; c < 4; ++c) {
        int4 val = *(const int4*)&tw[ql][(hi * 4 + c) * 8];
        *(int4*)(Xg + ((size_t)b * NSEQ + q0 + ql) * 512 + h * 64 + (hi * 4 + c) * 8) = val;
    }
}

// ---------------- K4: output projection + bias + BN (128x64, global_load_lds staging) ----------------
__global__ __launch_bounds__(256) void out_gemm(
    const short* __restrict__ Xg, const short* __restrict__ Wo,
    const float* __restrict__ bo, const float* __restrict__ og, const float* __restrict__ ob,
    const float* __restrict__ om, const float* __restrict__ ov,
    float* __restrict__ out)
{
    __shared__ short At[128][32];
    __shared__ short Bt[64][32];
    int mt = blockIdx.x, nt = blockIdx.y;
    int t = threadIdx.x, wave = t >> 6, lane = t & 63;
    int wr = wave >> 1, wc = wave & 1, lr = lane & 15, lg = lane >> 4;
    int row0 = mt * 128, o0 = nt * 64;

    int srow = lane >> 2, scol = (lane & 3) * 8;
    int rA0 = (wave * 2) * 16 + srow, rA1 = (wave * 2 + 1) * 16 + srow;
    int rB  = wave * 16 + srow;
    short* lA0 = &At[0][0] + (wave * 2) * 512;
    short* lA1 = &At[0][0] + (wave * 2 + 1) * 512;
    short* lB  = &Bt[0][0] + wave * 512;

    f32x4 acc[4][2];
#pragma unroll
    for (int m = 0; m < 4; ++m)
#pragma unroll
        for (int n = 0; n < 2; ++n) acc[m][n] = (f32x4){0.f, 0.f, 0.f, 0.f};

    for (int k0 = 0; k0 < 512; k0 += 32) {
        gload16(Xg + (size_t)(row0 + rA0) * 512 + k0 + scol, lA0);
        gload16(Xg + (size_t)(row0 + rA1) * 512 + k0 + scol, lA1);
        gload16(Wo + (size_t)(o0 + rB) * 512 + k0 + scol, lB);
        __syncthreads();
        bf16x8 af[4], bfr[2];
#pragma unroll
        for (int m = 0; m < 4; ++m) af[m] = *(const bf16x8*)&At[wr * 64 + m * 16 + lr][lg * 8];
#pragma unroll
        for (int n = 0; n < 2; ++n) bfr[n] = *(const bf16x8*)&Bt[wc * 32 + n * 16 + lr][lg * 8];
#pragma unroll
        for (int m = 0; m < 4; ++m)
#pragma unroll
            for (int n = 0; n < 2; ++n)
                acc[m][n] = MFMA16(af[m], bfr[n], acc[m][n]);
        __syncthreads();
    }

    int b = row0 >> 10;
    int pbase = row0 & 1023;
#pragma unroll
    for (int n = 0; n < 2; ++n) {
        int o = o0 + wc * 32 + n * 16 + lr;
        float inv = og[o] * rsqrtf(ov[o] + 1e-5f);
        float off = bo[o] * inv + ob[o] - om[o] * inv;
        float* dst = out + ((size_t)b * 256 + o) * 1024 + pbase;
#pragma unroll
        for (int m = 0; m < 4; ++m)
#pragma unroll
            for (int r = 0; r < 4; ++r) {
                int p = wr * 64 + m * 16 + lg * 4 + r;
                dst[p] = acc[m][n][r] * inv + off;
            }
    }
}

// ---------------- launch ----------------
extern "C" void kernel_launch(void* const* d_in, const int* in_sizes, int n_in,
                              void* d_out, int out_size, void* d_ws, size_t ws_size,
                              hipStream_t stream) {
    const float* x     = (const float*)d_in[0];
    const float* wq    = (const float*)d_in[1];
    const float* qgam  = (const float*)d_in[2];
    const float* qbet  = (const float*)d_in[3];
    const float* qmu   = (const float*)d_in[4];
    const float* qvar  = (const float*)d_in[5];
    const float* wk    = (const float*)d_in[6];
    const float* kgam  = (const float*)d_in[7];
    const float* kbet  = (const float*)d_in[8];
    const float* kmu   = (const float*)d_in[9];
    const float* kvar  = (const float*)d_in[10];
    const float* wv    = (const float*)d_in[11];
    const float* vgam  = (const float*)d_in[12];
    const float* vbet  = (const float*)d_in[13];
    const float* vmu   = (const float*)d_in[14];
    const float* vvar  = (const float*)d_in[15];
    const float* wo    = (const float*)d_in[16];
    const float* bo    = (const float*)d_in[17];
    const float* ogam  = (const float*)d_in[18];
    const float* obet  = (const float*)d_in[19];
    const float* omu   = (const float*)d_in[20];
    const float* ovar  = (const float*)d_in[21];
    const float* pos_emb = (const float*)d_in[22];
    // d_in[23] pos_indices: recomputed analytically in-kernel

    char* ws = (char*)d_ws;
    short* Wqkv = (short*)(ws + 0);          // 524288
    float* Bqkv = (float*)(ws + 524288);     // 4096
    short* Wo   = (short*)(ws + 528384);     // 262144
    short* Xt   = (short*)(ws + 790528);     // 4 MB
    short* Qd   = (short*)(ws + 4984832);    // 4 MB
    short* Kd   = (short*)(ws + 9179136);    // 4 MB
    short* Vtd  = (short*)(ws + 13373440);   // 8 MB
    short* Xg   = (short*)(ws + 21762048);   // 8 MB (end 30150656)

    prep_trans_kernel<<<1792, 256, 0, stream>>>(x, Xt,
                                                wq, qgam, qbet, qmu, qvar,
                                                wk, kgam, kbet, kmu, kvar,
                                                wv, vgam, vbet, vmu, vvar,
                                                wo, Wqkv, Bqkv, Wo);
    qkv_gemm<<<dim3(8, 8, NB), 256, 0, stream>>>(Xt, Wqkv, Bqkv, Qd, Kd, Vtd);
    attn_kernel<<<512, 256, 0, stream>>>(Qd, Kd, Vtd, pos_emb, Xg);
    out_gemm<<<dim3(64, 4), 256, 0, stream>>>(Xg, Wo, bo, ogam, obet, omu, ovar, (float*)d_out);
}